// Round 7
// baseline (406.196 us; speedup 1.0000x reference)
//
#include <hip/hip_runtime.h>
#include <cmath>
#include <cstdint>
#include <cstddef>

#define NT 17
#define NP 45
#define CH 8
// B=64, S=512, H=768

__device__ __forceinline__ float rlane(float v, int k) {
    return __int_as_float(__builtin_amdgcn_readlane(__float_as_int(v), k));
}

// Broadcast lane k's value to all lanes via the LDS crossbar (ds_bpermute):
// VGPR->VGPR, no SGPR write hazard, no LDS memory, pipelined on the DS pipe.
__device__ __forceinline__ float bperm(float v, int k) {
    return __int_as_float(__builtin_amdgcn_ds_bpermute(k * 4, __float_as_int(v)));
}

// 16B async global->LDS DMA (no VGPR round-trip, no ds_write instruction).
__device__ __forceinline__ void gload16(const float* g, float* l) {
    __builtin_amdgcn_global_load_lds(
        (const __attribute__((address_space(1))) void*)g,
        (__attribute__((address_space(3))) void*)l, 16, 0, 0);
}

// ---------------------------------------------------------------------------
// Kernel 0: pack W into Wpk[768][64] (17 tag cols | 45 pos cols | 2 zero pad)
// so Bs staging has contiguous 16B-aligned source rows for global_load_lds.
// ---------------------------------------------------------------------------
__global__ __launch_bounds__(256) void pack_w(
    const float* __restrict__ Wt, const float* __restrict__ Wp,
    float* __restrict__ Wpk)
{
    int i = blockIdx.x * 256 + threadIdx.x;
    if (i >= 768 * 64) return;
    int k = i >> 6, c = i & 63;
    float v = 0.f;
    if (c < NT) v = Wt[k * NT + c];
    else if (c < NT + NP) v = Wp[k * NP + (c - NT)];
    Wpk[i] = v;
}

// ---------------------------------------------------------------------------
// Kernel 1: logits = hidden @ [W_tag | W_pos] + bias   (f32 vector GEMM)
// DMA-staged tiles, source-side XOR swizzle on As, zero LDS staging instrs,
// conflict-free reads. Accumulation per output is the identical strictly-
// ascending-k fmaf chain with bias added last -> logits bitwise unchanged.
// ---------------------------------------------------------------------------
__global__ __launch_bounds__(256) void gemm_logits(
    const float* __restrict__ hidden, const float* __restrict__ Wpk,
    const float* __restrict__ bt, const float* __restrict__ bp,
    float* __restrict__ tagL, float* __restrict__ posL)
{
    __shared__ __align__(16) float As[64 * 32];
    __shared__ __align__(16) float Bs[32 * 64];
    const int tid = threadIdx.x;
    const int rg = tid >> 4;          // 0..15 (row group)
    const int cg = tid & 15;          // 0..15 (col group)
    const int srg = rg & 7;
    const int row0 = blockIdx.x * 64;

    float acc[4][4];
#pragma unroll
    for (int a = 0; a < 4; ++a)
#pragma unroll
        for (int b = 0; b < 4; ++b) acc[a][b] = 0.f;

    // staging indices (all dest offsets are tid*16B -> DMA-linear per wave)
    const int arow = tid >> 3;        // 0..31
    const int aq   = tid & 7;         // 0..7  (k-group slot)
    const int bk   = tid >> 4;        // 0..15
    const int bc4  = tid & 15;        // 0..15

#pragma unroll 1
    for (int kc = 0; kc < 768; kc += 32) {
        {   // As rows 0..31 and 32..63: source k-group = slot ^ ((row>>2)&7)
            int r0 = arow;
            int s0 = (r0 >> 2) & 7;
            gload16(hidden + (size_t)(row0 + r0) * 768 + kc + ((aq ^ s0) << 2),
                    As + r0 * 32 + aq * 4);
            int r1 = 32 + arow;
            int s1 = (r1 >> 2) & 7;
            gload16(hidden + (size_t)(row0 + r1) * 768 + kc + ((aq ^ s1) << 2),
                    As + r1 * 32 + aq * 4);
            // Bs rows kc..kc+31 from packed W
            gload16(Wpk + (size_t)(kc + bk) * 64 + bc4 * 4,
                    Bs + bk * 64 + bc4 * 4);
            gload16(Wpk + (size_t)(kc + 16 + bk) * 64 + bc4 * 4,
                    Bs + (16 + bk) * 64 + bc4 * 4);
        }
        __syncthreads();              // implicit vmcnt(0): DMA landed
#pragma unroll
        for (int k4 = 0; k4 < 8; ++k4) {
            const int qb = ((k4 ^ srg) << 2);   // swizzled As slot offset
            float a_[4][4], b_[4][4];
#pragma unroll
            for (int jr = 0; jr < 4; ++jr) {
                float4 t = *(const float4*)(As + (rg * 4 + jr) * 32 + qb);
                a_[jr][0] = t.x; a_[jr][1] = t.y; a_[jr][2] = t.z; a_[jr][3] = t.w;
            }
#pragma unroll
            for (int kk = 0; kk < 4; ++kk) {
                float4 t = *(const float4*)(Bs + (k4 * 4 + kk) * 64 + cg * 4);
                b_[kk][0] = t.x; b_[kk][1] = t.y; b_[kk][2] = t.z; b_[kk][3] = t.w;
            }
#pragma unroll
            for (int kk = 0; kk < 4; ++kk)      // k strictly ascending
#pragma unroll
                for (int jr = 0; jr < 4; ++jr)
#pragma unroll
                    for (int jc = 0; jc < 4; ++jc)
                        acc[jr][jc] = fmaf(a_[jr][kk], b_[kk][jc], acc[jr][jc]);
        }
        __syncthreads();              // protect LDS before next-chunk DMA
    }
#pragma unroll
    for (int jr = 0; jr < 4; ++jr) {
        size_t r = (size_t)row0 + rg * 4 + jr;
#pragma unroll
        for (int jc = 0; jc < 4; ++jc) {
            int c = cg * 4 + jc;
            if (c < NT) tagL[r * NT + c] = acc[jr][jc] + bt[c];
            else if (c < NT + NP) posL[r * NP + (c - NT)] = acc[jr][jc] + bp[c - NT];
        }
    }
}

// ---------------------------------------------------------------------------
// Kernel 2: the four CRF scans. One wave per (b, role); 256 blocks x 64 thr.
// Round-7: the all-to-all broadcast of the state vector now uses
// ds_bpermute (VGPR->VGPR crossbar). Round-6 falsified the register-
// residency theory (88-VGPR and 40-VGPR builds both ran 147us); the
// invariant cost is the broadcast: v_readlane writes SGPRs, and each
// readlane->SGPR->v_fma pair carries a VALU-SGPR hazard a lone wave
// (1/SIMD) cannot hide (~6.8 cy/op observed). bpermute has VGPR
// destinations (no SGPR hazard, no SGPR-count serialization) and its 48
// independent DS-pipe ops pipeline with counted lgkmcnt waits under the
// fmaf chains. bpermute is a pure bit-permute and the accumulation order
// is untouched -> results stay bitwise identical.
// NLL runs in LINEAR space (f = exp(e) off-chain per chunk; exact
// power-of-2 rescale per chunk via readlane+fmax tree).
// ---------------------------------------------------------------------------
template <int T, int PAD>
__device__ void nll_scan(int b,
    const float* __restrict__ logits, const int* __restrict__ mask,
    const int* __restrict__ targ, const float* __restrict__ start,
    const float* __restrict__ trans, const float* __restrict__ endv,
    float* __restrict__ den, float* __restrict__ num)
{
    const int lane = threadIdx.x;
    const int jj = (lane < T) ? lane : (T - 1);
    float Ecol[PAD];
#pragma unroll
    for (int i = 0; i < PAD; ++i) Ecol[i] = (i < T) ? __expf(trans[i * T + jj]) : 0.f;
    const float esjj = __expf(start[jj]);
    const float* eptr = logits + (size_t)b * 512 * T + jj;
    const int* mptr = mask + b * 512;

    float eb[CH], en[CH], fb[CH];
    int mb, mn = 0;
#pragma unroll
    for (int k = 0; k < CH; ++k) { eb[k] = eptr[k * T]; en[k] = 0.f; }
    mb = mptr[lane & (CH - 1)];

    float a = 0.f;
    int excorr = 0;
    for (int c = 0; c < 64; ++c) {
        unsigned long long kb = __ballot(mb > 0);
        if (c < 63) {
            const float* ep2 = eptr + (c + 1) * CH * T;
#pragma unroll
            for (int k = 0; k < CH; ++k) en[k] = ep2[k * T];
            mn = mptr[(c + 1) * CH + (lane & (CH - 1))];
        }
#pragma unroll
        for (int k = 0; k < CH; ++k) fb[k] = __expf(eb[k]);   // off-chain
#pragma unroll
        for (int s = 0; s < CH; ++s) {
            // bpermute broadcast of a; lanes >= T hold a duplicate of column
            // T-1 and Ecol there is 0, so fma contributes exactly 0.
            float d0 = 0.f, d1 = 0.f, d2 = 0.f, d3 = 0.f;
#pragma unroll
            for (int q = 0; q < PAD / 4; ++q) {
                d0 = fmaf(bperm(a, 4 * q + 0), Ecol[4 * q + 0], d0);
                d1 = fmaf(bperm(a, 4 * q + 1), Ecol[4 * q + 1], d1);
                d2 = fmaf(bperm(a, 4 * q + 2), Ecol[4 * q + 2], d2);
                d3 = fmaf(bperm(a, 4 * q + 3), Ecol[4 * q + 3], d3);
            }
            float cand = ((d0 + d1) + (d2 + d3)) * fb[s];
            bool keep = (kb >> s) & 1ULL;
            bool first = (c == 0) && (s == 0);
            a = first ? (esjj * fb[0]) : (keep ? cand : a);
        }
        // exact power-of-2 rescale; wave-uniform max via readlane tree.
        // Pad lanes mirror lane T-1, so including lanes up to the next
        // multiple of 4 gives the exact same max value.
        float mv0 = rlane(a, 0), mv1 = rlane(a, 1);
        float mv2 = rlane(a, 2), mv3 = rlane(a, 3);
#pragma unroll
        for (int i = 4; i < T; i += 4) {
            mv0 = fmaxf(mv0, rlane(a, i + 0));
            mv1 = fmaxf(mv1, rlane(a, i + 1));
            mv2 = fmaxf(mv2, rlane(a, i + 2));
            mv3 = fmaxf(mv3, rlane(a, i + 3));
        }
        float m = fmaxf(fmaxf(mv0, mv1), fmaxf(mv2, mv3));
        int ex;
        (void)frexpf(m, &ex);
        a *= ldexpf(1.0f, -ex);
        excorr += ex;
#pragma unroll
        for (int k = 0; k < CH; ++k) eb[k] = en[k];
        mb = mn;
    }
    // denominator: log(sum_j a_j * exp(end_j)) + excorr*ln2
    float term = (lane < T) ? a * __expf(endv[lane]) : 0.f;
#pragma unroll
    for (int o = 32; o; o >>= 1) term += __shfl_xor(term, o);
    if (lane == 0) den[b] = __logf(term) + (float)excorr * 0.69314718056f;

    // numerator (raw logits; lse cancels in num-den)
    float part = 0.f; int Lc = 0;
    for (int t = lane; t < 512; t += 64) {
        int mt = mask[b * 512 + t];
        Lc += (mt > 0);
        if (t >= 1 && mt > 0) {
            int tg = targ[b * 512 + t];
            int pg = targ[b * 512 + t - 1];
            part += trans[pg * T + tg] + logits[((size_t)b * 512 + t) * T + tg];
        }
    }
#pragma unroll
    for (int o = 32; o; o >>= 1) { part += __shfl_xor(part, o); Lc += __shfl_xor(Lc, o); }
    if (lane == 0) {
        int t0g = targ[b * 512];
        num[b] = start[t0g] + logits[(size_t)b * 512 * T + t0g]
               + part + endv[targ[b * 512 + Lc - 1]];
    }
}

// Viterbi forward, max only; stores score vectors for later argmax recompute.
// Same bpermute broadcast; max is order-exact so scores are bitwise
// unchanged (hist recompute stays bit-identical).
template <int T, int PAD>
__device__ void vit_fwd(int b,
    const float* __restrict__ logits, const int* __restrict__ mask,
    const float* __restrict__ start, const float* __restrict__ trans,
    float* __restrict__ score)
{
    const int lane = threadIdx.x;
    const int jj = (lane < T) ? lane : (T - 1);
    float Tcol[PAD];
#pragma unroll
    for (int i = 0; i < PAD; ++i) Tcol[i] = (i < T) ? trans[i * T + jj] : -1e30f;
    const float sjj = start[jj];
    const float* eptr = logits + (size_t)b * 512 * T + jj;
    const int* mptr = mask + b * 512;
    float* sptr = score + (size_t)b * 512 * T + lane;

    float eb[CH], en[CH];
    int mb, mn = 0;
#pragma unroll
    for (int k = 0; k < CH; ++k) { eb[k] = eptr[k * T]; en[k] = 0.f; }
    mb = mptr[lane & (CH - 1)];

    float sc = 0.f;
    for (int c = 0; c < 64; ++c) {
        unsigned long long kb = __ballot(mb > 0);
        if (c < 63) {
            const float* ep2 = eptr + (c + 1) * CH * T;
#pragma unroll
            for (int k = 0; k < CH; ++k) en[k] = ep2[k * T];
            mn = mptr[(c + 1) * CH + (lane & (CH - 1))];
        }
#pragma unroll
        for (int s = 0; s < CH; ++s) {
            float m = -1e30f;
#pragma unroll
            for (int q = 0; q < PAD / 4; ++q) {
                float ca = bperm(sc, 4 * q + 0) + Tcol[4 * q + 0];
                float cb = bperm(sc, 4 * q + 1) + Tcol[4 * q + 1];
                float cc = bperm(sc, 4 * q + 2) + Tcol[4 * q + 2];
                float cd = bperm(sc, 4 * q + 3) + Tcol[4 * q + 3];
                m = fmaxf(m, fmaxf(ca, cb));   // -> v_max3
                m = fmaxf(m, fmaxf(cc, cd));
            }
            float nxt = m + eb[s];
            bool keep = (kb >> s) & 1ULL;
            bool first = (c == 0) && (s == 0);
            sc = first ? (sjj + eb[0]) : (keep ? nxt : sc);
            if (lane < T) sptr[(size_t)(c * CH + s) * T] = sc;
        }
#pragma unroll
        for (int k = 0; k < CH; ++k) eb[k] = en[k];
        mb = mn;
    }
}

__global__ __launch_bounds__(64, 1) void scan_kernel(
    const float* tagL, const float* posL, const int* mask,
    const int* tgT, const int* tgP,
    const float* startT, const float* transT, const float* endT,
    const float* startP, const float* transP, const float* endP,
    float* scoreT, float* scoreP,
    float* denT, float* denP, float* numT, float* numP)
{
    int bid = blockIdx.x;
    if (bid < 64)
        vit_fwd<NP, 48>(bid, posL, mask, startP, transP, scoreP);
    else if (bid < 128)
        nll_scan<NP, 48>(bid - 64, posL, mask, tgP, startP, transP, endP, denP, numP);
    else if (bid < 192)
        vit_fwd<NT, 20>(bid - 128, tagL, mask, startT, transT, scoreT);
    else
        nll_scan<NT, 20>(bid - 192, tagL, mask, tgT, startT, transT, endT, denT, numT);
}

// ---------------------------------------------------------------------------
// Kernel 3: recompute Viterbi backpointers massively parallel over (b,t).
// Bit-identical adds vs forward pass => identical argmax.
// ---------------------------------------------------------------------------
template <int T>
__device__ void hist_block(int b, int tc,
    const float* __restrict__ score, const int* __restrict__ mask,
    const float* __restrict__ trans, unsigned char* __restrict__ hist)
{
    const int wave = threadIdx.x >> 6;
    const int lane = threadIdx.x & 63;
    const int jj = (lane < T) ? lane : (T - 1);
    float Tcol[T];
#pragma unroll
    for (int i = 0; i < T; ++i) Tcol[i] = trans[i * T + jj];
    for (int q = 0; q < 16; ++q) {
        int t = tc * 64 + wave * 16 + q;
        if (t < 1) continue;
        int mt = mask[b * 512 + t];
        int hv;
        if (mt > 0) {
            float sv = score[((size_t)b * 512 + t - 1) * T + jj];
            float mx = -1e30f; int am = 0;
#pragma unroll
            for (int i = 0; i < T; ++i) {
                float cand = rlane(sv, i) + Tcol[i];
                bool g = cand > mx;            // strict > keeps FIRST max
                mx = g ? cand : mx;
                am = g ? i : am;
            }
            hv = am;
        } else {
            hv = jj;                           // identity when masked
        }
        if (lane < T)
            hist[((size_t)b * 512 + (t - 1)) * T + lane] = (unsigned char)hv;
    }
}

__global__ __launch_bounds__(256) void hist_kernel(
    const float* scoreT, const float* scoreP, const int* mask,
    const float* transT, const float* transP,
    unsigned char* histT, unsigned char* histP)
{
    int blk = blockIdx.x;
    if (blk < 512) hist_block<NP>(blk >> 3, blk & 7, scoreP, mask, transP, histP);
    else { blk -= 512; hist_block<NT>(blk >> 3, blk & 7, scoreT, mask, transT, histT); }
}

// ---------------------------------------------------------------------------
// Kernel 4: backtrace with pointer-jump composition (serial chain 511 -> 63).
// Block 128 additionally computes the losses (merged finalize).
// ---------------------------------------------------------------------------
template <int T>
__device__ void backtrace(int b, const float* __restrict__ score,
    const unsigned char* __restrict__ hist, const float* __restrict__ endv,
    float* __restrict__ outp, unsigned char* sh)
{
    unsigned char* h  = sh;                    // 512*T
    unsigned char* g2 = sh + 512 * T;          // rows 0..509
    unsigned char* g4 = sh + 1024 * T;         // 127 rows (r = 3+4*a4)
    unsigned char* g8 = sh + 1024 * T + 128 * T; // 63 rows (r = 503-8a)
    unsigned char* pr = sh + 1024 * T + 192 * T; // 512
    const int lane = threadIdx.x;

    {   // stage hist to LDS (b-stride = 512*T bytes, 16B multiple)
        const int4* src = (const int4*)(hist + (size_t)b * 512 * T);
        int4* dst = (int4*)h;
        int n16 = (512 * T) / 16;
        for (int i = lane; i < n16; i += 64) dst[i] = src[i];
    }
    __syncthreads();
    // g2[r][i] = h[r][h[r+1][i]]  (maps cur at t=r+2 -> t=r)
    for (int idx = lane; idx < 510 * T; idx += 64) {
        int r = idx / T, i = idx - r * T;
        g2[idx] = h[r * T + h[(r + 1) * T + i]];
    }
    __syncthreads();
    // g4 rows r = 3+4*a4: g4[a4][i] = g2[r][ g2[r+2][i] ]  (t=r+4 -> r)
    for (int idx = lane; idx < 127 * T; idx += 64) {
        int a4 = idx / T, i = idx - a4 * T;
        int r = 3 + 4 * a4;
        g4[idx] = g2[r * T + g2[(r + 2) * T + i]];
    }
    __syncthreads();
    // g8 rows r = 503-8a: g8[a][i] = g4row(r)[ g4row(r+4)[i] ]  (t=r+8 -> r)
    for (int idx = lane; idx < 63 * T; idx += 64) {
        int a = idx / T, i = idx - a * T;
        int r = 503 - 8 * a;
        int a4lo = (r - 3) >> 2, a4hi = (r + 1) >> 2;
        g8[idx] = g4[a4lo * T + g4[a4hi * T + i]];
    }
    // last = first-index argmax(score[511] + end)
    float v = (lane < T) ? (score[((size_t)b * 512 + 511) * T + lane] + endv[lane]) : -1e30f;
    float mx = v;
#pragma unroll
    for (int o = 32; o; o >>= 1) mx = fmaxf(mx, __shfl_xor(mx, o));
    unsigned long long bal = __ballot(v == mx);
    int cur = __ffsll(bal) - 1;
    __syncthreads();
    // phase A: serial anchor chain, 63 dependent LDS reads
    int myCur = 0;
    for (int a = 0; a < 64; ++a) {
        if (lane == a) myCur = cur;
        if (a < 63) cur = g8[a * T + cur];
    }
    // phase B: each lane fills its 8-step segment
    {
        int ta = 511 - 8 * lane;
        int j = myCur;
        pr[ta] = (unsigned char)j;
        int rlo = (lane == 63) ? 0 : (ta - 7);
        for (int r = ta - 1; r >= rlo; --r) {
            j = h[r * T + j];
            pr[r] = (unsigned char)j;
        }
    }
    __syncthreads();
    for (int k = lane; k < 512; k += 64)
        outp[(size_t)b * 512 + k] = (float)pr[k];
}

__global__ __launch_bounds__(64, 1) void backtrace_kernel(
    const float* scoreT, const float* scoreP,
    const unsigned char* histT, const unsigned char* histP,
    const float* endT, const float* endP,
    const float* numT, const float* denT,
    const float* numP, const float* denP, float* out)
{
    __shared__ __align__(16) unsigned char sh[1216 * NP + 576];
    int blk = blockIdx.x;
    if (blk < 64) backtrace<NP>(blk, scoreP, histP, endP, out + 32768, sh);
    else if (blk < 128) backtrace<NT>(blk - 64, scoreT, histT, endT, out, sh);
    else {
        // merged finalize: losses = -mean(num - den)
        int lane = threadIdx.x;
        float dT = numT[lane] - denT[lane];
        float dP = numP[lane] - denP[lane];
#pragma unroll
        for (int o = 32; o; o >>= 1) { dT += __shfl_xor(dT, o); dP += __shfl_xor(dP, o); }
        if (lane == 0) {
            out[65536] = -dT / 64.f;
            out[65537] = -dP / 64.f;
        }
    }
}

// ---------------------------------------------------------------------------
extern "C" void kernel_launch(void* const* d_in, const int* in_sizes, int n_in,
                              void* d_out, int out_size, void* d_ws, size_t ws_size,
                              hipStream_t stream)
{
    const float* hidden = (const float*)d_in[0];
    const int*   mask   = (const int*)d_in[1];
    const int*   tgT    = (const int*)d_in[2];
    const int*   tgP    = (const int*)d_in[3];
    const float* Wt     = (const float*)d_in[4];
    const float* bt     = (const float*)d_in[5];
    const float* Wp     = (const float*)d_in[6];
    const float* bp     = (const float*)d_in[7];
    const float* startT = (const float*)d_in[8];
    const float* transT = (const float*)d_in[9];
    const float* endT   = (const float*)d_in[10];
    const float* startP = (const float*)d_in[11];
    const float* transP = (const float*)d_in[12];
    const float* endP   = (const float*)d_in[13];

    float* ws     = (float*)d_ws;
    float* tagL   = ws;                         // 557056
    float* posL   = tagL + 557056;              // 1474560
    float* scoreT = posL + 1474560;             // 557056
    float* scoreP = scoreT + 557056;            // 1474560
    float* denT   = scoreP + 1474560;           // 64
    float* denP   = denT + 64;
    float* numT   = denP + 64;
    float* numP   = numT + 64;
    unsigned char* histT = (unsigned char*)(numP + 64);       // 64*512*17 B
    unsigned char* histP = histT + (size_t)64 * 512 * NT;     // 64*512*45 B
    float* out = (float*)d_out;

    // Wpk (768*64 floats) aliases scoreT: pack_w -> gemm (reads it) strictly
    // precede scan_kernel (which overwrites scoreT). Launch order on the
    // stream guarantees safety; no extra workspace needed.
    float* Wpk = scoreT;

    pack_w<<<192, 256, 0, stream>>>(Wt, Wp, Wpk);
    gemm_logits<<<512, 256, 0, stream>>>(hidden, Wpk, bt, bp, tagL, posL);
    scan_kernel<<<256, 64, 0, stream>>>(tagL, posL, mask, tgT, tgP,
        startT, transT, endT, startP, transP, endP,
        scoreT, scoreP, denT, denP, numT, numP);
    hist_kernel<<<1024, 256, 0, stream>>>(scoreT, scoreP, mask, transT, transP,
        histT, histP);
    backtrace_kernel<<<129, 64, 0, stream>>>(scoreT, scoreP, histT, histP,
        endT, endP, numT, denT, numP, denP, out);
}